// Round 8
// baseline (271.972 us; speedup 1.0000x reference)
//
#include <hip/hip_runtime.h>
#include <stdint.h>

#define N_ROWS 8192
#define H_DIM  1024
#define I_DIM  4096

typedef unsigned short u16;
typedef __bf16 bf16x8 __attribute__((ext_vector_type(8)));
typedef float f32x4 __attribute__((ext_vector_type(4)));
typedef u16 u16x4 __attribute__((ext_vector_type(4)));

#define BAR()   asm volatile("s_barrier" ::: "memory")
#define VMW(n)  asm volatile("s_waitcnt vmcnt(" #n ")" ::: "memory")

__device__ __forceinline__ u16 f2bf(float f) {
    union { float f; uint32_t u; } v; v.f = f;
    uint32_t u = v.u;
    u += 0x7FFFu + ((u >> 16) & 1u);   // RNE
    return (u16)(u >> 16);
}

__device__ __forceinline__ float bf2f(u16 h) {
    union { uint32_t u; float f; } v; v.u = ((uint32_t)h) << 16;
    return v.f;
}

__device__ __forceinline__ float gelu_tanh(float x) {
    float u = 0.7978845608028654f * (x + 0.044715f * x * x * x);
    u = fminf(fmaxf(u, -15.f), 15.f);
    float e = __expf(2.f * u);
    float t = (e - 1.f) / (e + 1.f);
    return 0.5f * x * (1.f + t);
}

// ---- global -> LDS direct (16B per lane) ----
__device__ __forceinline__ void load_lds16(const void* g, void* l) {
    auto gp = reinterpret_cast<const __attribute__((address_space(1))) uint32_t*>(
        reinterpret_cast<uintptr_t>(g));
    auto lp = reinterpret_cast<__attribute__((address_space(3))) uint32_t*>(
        static_cast<uint32_t>(reinterpret_cast<uintptr_t>(l)));
    __builtin_amdgcn_global_load_lds(gp, lp, 16, 0, 0);
}

// =====================================================================
// GEMM1 (TLP design): hid = gelu(xln·W1g^T+bg)*(xln·W1l^T+bl), bf16 out.
// Tile 128 rows x 128 hid-cols; 512 thr / 8 waves (2M x 4N); per-wave
// 64 rows x 32 hid x {gate,lin} -> acc = 64 VGPR. BK=32.
// LDS ring-3 x 24 KiB (A[128][32]@0, B[256][32]@4096 u16: rows 0-127 =
// gate cols, 128-255 = lin cols) = 72 KiB -> 2 blocks/CU = 16 waves.
// Schedule per kt: stage tile kt+2 (3 loads/thread) ; 8 ds_read ; 16
// MFMA ; VMW(3) ; BAR.  ONE barrier per K-32 tile -> waves/blocks slip
// (TLP covers LDS drain). Stage cover = 1 full tile-period (>=1200 cyc).
// swizzle: k-granule ^ ((row>>1)&3) (measured 0-conflict, r4-r7).
// =====================================================================
__global__ __launch_bounds__(512, 4) void gemm1_gated(
    const u16* __restrict__ A, const u16* __restrict__ W,
    const float* __restrict__ bias, u16* __restrict__ hid)
{
    __shared__ u16 lds[3 * 12288];     // 72 KiB
    const int t = threadIdx.x;
    const int lane = t & 63, wid = t >> 6;
    const int wm = wid >> 2, wn = wid & 3;
    const int g = lane >> 4, r16 = lane & 15;

    const int brow = blockIdx.y * 128;
    const int bcol = blockIdx.x * 128;

    // staging: thread t covers row t>>2 (A and B gate) and (t>>2)+128 (B lin)
    const int tr = t >> 2;
    const int swz8 = ((t & 3) ^ ((tr >> 1) & 3)) * 8;
    const u16* pA  = A + (size_t)(brow + tr) * H_DIM + swz8;
    const u16* pBg = W + (size_t)(bcol + tr) * H_DIM + swz8;           // gate col
    const u16* pBl = W + (size_t)(I_DIM + bcol + tr) * H_DIM + swz8;   // lin col
    const int dst = t * 8;

    // read offsets (u16 units within a buffer)
    const int sl  = (g ^ ((r16 >> 1) & 3)) * 8;
    const int rdA = (wm * 64 + r16) * 32 + sl;             // + m*512
    const int rdB = 4096 + (wn * 32 + r16) * 32 + sl;      // + n*512; lin +4096

    f32x4 accg[4][2] = {};
    f32x4 accl[4][2] = {};

#define STG1(S, k0) do { \
    load_lds16(pA  + (k0), (S) + dst); \
    load_lds16(pBg + (k0), (S) + 4096 + dst); \
    load_lds16(pBl + (k0), (S) + 8192 + dst); } while (0)

    // prologue: stage tiles 0,1 into buffers 0,1
    STG1(lds, 0);
    STG1(lds + 12288, 32);
    VMW(3); BAR();   // tile 0 landed; tile 1 in flight

    const int NT = H_DIM / 32;   // 32
    int bc = 0;
#pragma unroll 1
    for (int kt = 0; kt < NT; ++kt) {
        const u16* L = lds + bc * 12288;
        if (kt + 2 < NT) {
            u16* S = lds + ((bc + 2 >= 3) ? (bc - 1) : (bc + 2)) * 12288;
            STG1(S, (kt + 2) * 32);
        }
        bf16x8 af[4], bg[2], bl[2];
#pragma unroll
        for (int m = 0; m < 4; ++m) af[m] = *(const bf16x8*)(L + rdA + m * 512);
#pragma unroll
        for (int n = 0; n < 2; ++n) {
            bg[n] = *(const bf16x8*)(L + rdB + n * 512);
            bl[n] = *(const bf16x8*)(L + rdB + 4096 + n * 512);
        }
        __builtin_amdgcn_s_setprio(1);
#pragma unroll
        for (int m = 0; m < 4; ++m)
#pragma unroll
            for (int n = 0; n < 2; ++n) {
                accg[m][n] = __builtin_amdgcn_mfma_f32_16x16x32_bf16(af[m], bg[n], accg[m][n], 0, 0, 0);
                accl[m][n] = __builtin_amdgcn_mfma_f32_16x16x32_bf16(af[m], bl[n], accl[m][n], 0, 0, 0);
            }
        __builtin_amdgcn_s_setprio(0);
        if (kt + 2 < NT) { VMW(3); } else { VMW(0); }
        BAR();
        bc = (bc == 2) ? 0 : bc + 1;
    }
#undef STG1

    // epilogue: bias + gated gelu, bf16 store
#pragma unroll
    for (int n = 0; n < 2; ++n) {
        const int cg = bcol + wn * 32 + n * 16 + r16;
        const float bgv = bias[cg], blv = bias[I_DIM + cg];
#pragma unroll
        for (int m = 0; m < 4; ++m) {
            const int row = brow + wm * 64 + m * 16 + g * 4;
            u16* hp = hid + (size_t)row * I_DIM + cg;
#pragma unroll
            for (int r = 0; r < 4; ++r) {
                float gate = accg[m][n][r] + bgv;
                float lin  = accl[m][n][r] + blv;
                hp[(size_t)r * I_DIM] = f2bf(gelu_tanh(gate) * lin);
            }
        }
    }
}

// =====================================================================
// GEMM2 (TLP design): opb = hid·W2^T + b2 (bf16 out).
// Tile 128 x 128; 256 thr / 4 waves (2M x 2N); per-wave 64x64, acc 64.
// BK=32; LDS ring-3 x 16 KiB (A[128][32]@0, B[128][32]@4096 u16)
// = 48 KiB -> 3 blocks/CU = 12 waves. 4 loads/thread/tile; VMW(4);
// one barrier per tile. grid 512 = 2 blocks/CU resident (no rounds).
// =====================================================================
__global__ __launch_bounds__(256, 3) void gemm2_k(
    const u16* __restrict__ A, const u16* __restrict__ W,
    const float* __restrict__ bias, u16* __restrict__ opb)
{
    __shared__ u16 lds[3 * 8192];      // 48 KiB
    const int t = threadIdx.x;
    const int lane = t & 63, wid = t >> 6;
    const int wm = wid >> 1, wn = wid & 1;
    const int g = lane >> 4, r16 = lane & 15;

    const int brow = blockIdx.y * 128;
    const int bcol = blockIdx.x * 128;

    const int tr = t >> 2;             // 0..63
    const int swz8 = ((t & 3) ^ ((tr >> 1) & 3)) * 8;
    const u16* pA = A + (size_t)(brow + tr) * I_DIM + swz8;
    const u16* pB = W + (size_t)(bcol + tr) * I_DIM + swz8;
    const int dst = t * 8;             // rows 0..63 region

    const int sl  = (g ^ ((r16 >> 1) & 3)) * 8;
    const int rdA = (wm * 64 + r16) * 32 + sl;             // + m*512
    const int rdB = 4096 + (wn * 64 + r16) * 32 + sl;      // + n*512

    f32x4 acc[4][4] = {};

#define STG2(S, k0) do { \
    load_lds16(pA + (k0),                      (S) + dst); \
    load_lds16(pA + (size_t)64 * I_DIM + (k0), (S) + 2048 + dst); \
    load_lds16(pB + (k0),                      (S) + 4096 + dst); \
    load_lds16(pB + (size_t)64 * I_DIM + (k0), (S) + 6144 + dst); } while (0)

    STG2(lds, 0);
    STG2(lds + 8192, 32);
    VMW(4); BAR();

    const int NT = I_DIM / 32;   // 128
    int bc = 0;
#pragma unroll 1
    for (int kt = 0; kt < NT; ++kt) {
        const u16* L = lds + bc * 8192;
        if (kt + 2 < NT) {
            u16* S = lds + ((bc + 2 >= 3) ? (bc - 1) : (bc + 2)) * 8192;
            STG2(S, (kt + 2) * 32);
        }
        bf16x8 af[4], bf[4];
#pragma unroll
        for (int m = 0; m < 4; ++m) af[m] = *(const bf16x8*)(L + rdA + m * 512);
#pragma unroll
        for (int n = 0; n < 4; ++n) bf[n] = *(const bf16x8*)(L + rdB + n * 512);
        __builtin_amdgcn_s_setprio(1);
#pragma unroll
        for (int m = 0; m < 4; ++m)
#pragma unroll
            for (int n = 0; n < 4; ++n)
                acc[m][n] = __builtin_amdgcn_mfma_f32_16x16x32_bf16(af[m], bf[n], acc[m][n], 0, 0, 0);
        __builtin_amdgcn_s_setprio(0);
        if (kt + 2 < NT) { VMW(4); } else { VMW(0); }
        BAR();
        bc = (bc == 2) ? 0 : bc + 1;
    }
#undef STG2

#pragma unroll
    for (int n = 0; n < 4; ++n) {
        const int cg = bcol + wn * 64 + n * 16 + r16;
        const float bv = bias[cg];
#pragma unroll
        for (int m = 0; m < 4; ++m) {
            const int row = brow + wm * 64 + m * 16 + g * 4;
            u16* op = opb + (size_t)row * H_DIM + cg;
#pragma unroll
            for (int r = 0; r < 4; ++r)
                op[(size_t)r * H_DIM] = f2bf(acc[m][n][r] + bv);
        }
    }
}

// ---- block mean/var over one row of 1024 (256 threads x 4 elems) ----
__device__ __forceinline__ void block_mean_var(float s, float s2, float* red, int t,
                                               float& mu, float& var) {
#pragma unroll
    for (int off = 32; off > 0; off >>= 1) {
        s  += __shfl_down(s, off);
        s2 += __shfl_down(s2, off);
    }
    const int wid = t >> 6;
    if ((t & 63) == 0) { red[wid] = s; red[4 + wid] = s2; }
    __syncthreads();
    if (t == 0) {
        float a = red[0] + red[1] + red[2] + red[3];
        float b = red[4] + red[5] + red[6] + red[7];
        red[0] = a * (1.f / H_DIM);
        red[1] = b * (1.f / H_DIM);
    }
    __syncthreads();
    mu = red[0];
    var = red[1] - mu * mu;
}

// ---- fused prep: ln_pre (blocks 0..8191) + w1 cvt (8192..16383) +
//                  w2 cvt (16384..20479) ----
__global__ __launch_bounds__(256) void prep(
    const float* __restrict__ x, const float* __restrict__ lnw,
    const float* __restrict__ lnb, u16* __restrict__ xln,
    const float* __restrict__ w1, u16* __restrict__ w1b,
    const float* __restrict__ w2, u16* __restrict__ w2b)
{
    __shared__ float red[8];
    const int bid = blockIdx.x, t = threadIdx.x;
    if (bid < N_ROWS) {
        const float4 v = reinterpret_cast<const float4*>(x + (size_t)bid * H_DIM)[t];
        float mu, var;
        block_mean_var(v.x + v.y + v.z + v.w,
                       v.x * v.x + v.y * v.y + v.z * v.z + v.w * v.w, red, t, mu, var);
        const float rstd = rsqrtf(var + 1e-5f);
        const float4 wv = reinterpret_cast<const float4*>(lnw)[t];
        const float4 bv = reinterpret_cast<const float4*>(lnb)[t];
        u16x4 o;
        o.x = f2bf((v.x - mu) * rstd * wv.x + bv.x);
        o.y = f2bf((v.y - mu) * rstd * wv.y + bv.y);
        o.z = f2bf((v.z - mu) * rstd * wv.z + bv.z);
        o.w = f2bf((v.w - mu) * rstd * wv.w + bv.w);
        reinterpret_cast<u16x4*>(xln + (size_t)bid * H_DIM)[t] = o;
    } else if (bid < N_ROWS + 8192) {
        const int i = (bid - N_ROWS) * 256 + t;
        const float4 v = reinterpret_cast<const float4*>(w1)[i];
        u16x4 o = { f2bf(v.x), f2bf(v.y), f2bf(v.z), f2bf(v.w) };
        reinterpret_cast<u16x4*>(w1b)[i] = o;
    } else {
        const int i = (bid - N_ROWS - 8192) * 256 + t;
        const float4 v = reinterpret_cast<const float4*>(w2)[i];
        u16x4 o = { f2bf(v.x), f2bf(v.y), f2bf(v.z), f2bf(v.w) };
        reinterpret_cast<u16x4*>(w2b)[i] = o;
    }
}

// post-LN over bf16 'op' rows + fp32 residual add
__global__ void ln_post_res(const u16* __restrict__ op, const float* __restrict__ w,
                            const float* __restrict__ b, const float* __restrict__ x,
                            float* __restrict__ out)
{
    __shared__ float red[8];
    const int row = blockIdx.x, t = threadIdx.x;
    const u16x4 hv = reinterpret_cast<const u16x4*>(op + (size_t)row * H_DIM)[t];
    float4 v;
    v.x = bf2f(hv.x); v.y = bf2f(hv.y); v.z = bf2f(hv.z); v.w = bf2f(hv.w);
    float mu, var;
    block_mean_var(v.x + v.y + v.z + v.w,
                   v.x * v.x + v.y * v.y + v.z * v.z + v.w * v.w, red, t, mu, var);
    const float rstd = rsqrtf(var + 1e-5f);
    const float4 wv = reinterpret_cast<const float4*>(w)[t];
    const float4 bv = reinterpret_cast<const float4*>(b)[t];
    const float4 xv = reinterpret_cast<const float4*>(x + (size_t)row * H_DIM)[t];
    float4 o;
    o.x = (v.x - mu) * rstd * wv.x + bv.x + xv.x;
    o.y = (v.y - mu) * rstd * wv.y + bv.y + xv.y;
    o.z = (v.z - mu) * rstd * wv.z + bv.z + xv.z;
    o.w = (v.w - mu) * rstd * wv.w + bv.w + xv.w;
    reinterpret_cast<float4*>(out + (size_t)row * H_DIM)[t] = o;
}

extern "C" void kernel_launch(void* const* d_in, const int* in_sizes, int n_in,
                              void* d_out, int out_size, void* d_ws, size_t ws_size,
                              hipStream_t stream)
{
    const float* x   = (const float*)d_in[0];
    const float* lnw = (const float*)d_in[1];
    const float* lnb = (const float*)d_in[2];
    const float* w1  = (const float*)d_in[3];
    const float* b1  = (const float*)d_in[4];
    const float* w2  = (const float*)d_in[5];
    const float* b2  = (const float*)d_in[6];
    const float* pw  = (const float*)d_in[7];
    const float* pb  = (const float*)d_in[8];
    float* out = (float*)d_out;

    // Workspace layout (104 MiB peak; proven r7):
    //   xln [0,16M) | w1b [16,32M) | hid [32,96M) | w2b [96,104M)
    //   opb over dead xln [0,16M) after gemm1.
    char* ws = (char*)d_ws;
    u16* xln = (u16*)(ws);
    u16* w1b = (u16*)(ws + (16u << 20));
    u16* hid = (u16*)(ws + (32u << 20));
    u16* w2b = (u16*)(ws + (96u << 20));
    u16* opb = (u16*)(ws);

    prep<<<20480, 256, 0, stream>>>(x, lnw, lnb, xln, w1, w1b, w2, w2b);
    gemm1_gated<<<dim3(I_DIM / 128, N_ROWS / 128), 512, 0, stream>>>(xln, w1b, b1, hid);
    gemm2_k<<<dim3(H_DIM / 128, N_ROWS / 128), 256, 0, stream>>>(hid, w2b, b2, opb);
    ln_post_res<<<N_ROWS, 256, 0, stream>>>(opb, pw, pb, x, out);
}